// Round 16
// baseline (223.861 us; speedup 1.0000x reference)
//
#include <hip/hip_runtime.h>

// ---------------- problem constants ----------------
#define Bb 8
#define Tt 1024
#define Hh 8
#define DKk 64
#define NFf 512
#define DCc 256

typedef _Float16 v2h __attribute__((ext_vector_type(2)));
typedef _Float16 v4h __attribute__((ext_vector_type(4)));
typedef _Float16 v8h __attribute__((ext_vector_type(8)));
typedef float    v4f __attribute__((ext_vector_type(4)));
typedef float    v16f __attribute__((ext_vector_type(16)));

#define MFMA32(a,b,c) __builtin_amdgcn_mfma_f32_16x16x32_f16((a),(b),(c),0,0,0)
#define MFMA3216(a,b,c) __builtin_amdgcn_mfma_f32_32x32x16_f16((a),(b),(c),0,0,0)

// scale folded into q: 1/sqrt(64) * log2(e)  (scores live in log2 domain)
#define SCQ 0.1803368801111f

__device__ inline void st8(_Float16* dst, v8h x){
    *(v4h*)dst     = __builtin_shufflevector(x,x,0,1,2,3);
    *(v4h*)(dst+4) = __builtin_shufflevector(x,x,4,5,6,7);
}

__device__ inline v8h cvt8(float4 a, float4 b){
    v8h r;
    r[0]=(_Float16)a.x; r[1]=(_Float16)a.y; r[2]=(_Float16)a.z; r[3]=(_Float16)a.w;
    r[4]=(_Float16)b.x; r[5]=(_Float16)b.y; r[6]=(_Float16)b.z; r[7]=(_Float16)b.w;
    return r;
}

// XOR swizzle for [R][64] half LDS tiles; keeps 8-half granularity
__device__ inline int swz(int r, int c){ return (r*64 + c) ^ ((r&7)<<3); }

// ---------------- LayerNorm: x (8192,512) fp32 -> xn fp16 ----------------
__global__ __launch_bounds__(256) void k_ln(const float* __restrict__ x,
                                            const float* __restrict__ g,
                                            const float* __restrict__ be,
                                            _Float16* __restrict__ xn){
    int row = blockIdx.x; int tid = threadIdx.x;
    const float* xr = x + (size_t)row*512;
    float2 v = reinterpret_cast<const float2*>(xr)[tid];
    float s = v.x + v.y, sq = v.x*v.x + v.y*v.y;
    for (int off=32; off; off>>=1){ s += __shfl_down(s, off); sq += __shfl_down(sq, off); }
    __shared__ float ws_[4], wq_[4];
    __shared__ float mu_s, rs_s;
    int wid = tid>>6, lid = tid&63;
    if (lid==0){ ws_[wid]=s; wq_[wid]=sq; }
    __syncthreads();
    if (tid==0){
        float S=0,Q=0;
        for(int i=0;i<4;i++){S+=ws_[i];Q+=wq_[i];}
        float mu = S*(1.f/512.f);
        float var = Q*(1.f/512.f)-mu*mu;
        mu_s=mu; rs_s=rsqrtf(var+1e-5f);
    }
    __syncthreads();
    float mu=mu_s, rs=rs_s;
    float2 gv = reinterpret_cast<const float2*>(g)[tid];
    float2 bv = reinterpret_cast<const float2*>(be)[tid];
    v2h o; o[0] = (_Float16)((v.x-mu)*rs*gv.x + bv.x);
           o[1] = (_Float16)((v.y-mu)*rs*gv.y + bv.y);
    reinterpret_cast<v2h*>(xn + (size_t)row*512)[tid] = o;
}

// ---------------- prep: 4x weight transpose + Wc->fp16 + zero + bcq init -----
__global__ __launch_bounds__(256) void k_prep(const float* __restrict__ Wk,
                                              const float* __restrict__ Wv,
                                              const float* __restrict__ Wo,
                                              const float* __restrict__ Wq,
                                              _Float16* __restrict__ WkT,
                                              _Float16* __restrict__ WvT,
                                              _Float16* __restrict__ WoT,
                                              _Float16* __restrict__ WqT,
                                              const float* __restrict__ Wc,
                                              _Float16* __restrict__ WcH,
                                              const float* __restrict__ bq,
                                              float* __restrict__ bcq,
                                              float* __restrict__ zero){
    __shared__ float tile[64][65];
    int z = blockIdx.z;
    int tid = threadIdx.x;
    if (z < 4){
        const float* W = (z==0)?Wk:(z==1)?Wv:(z==2)?Wo:Wq;
        _Float16*  WT = (z==0)?WkT:(z==1)?WvT:(z==2)?WoT:WqT;
        int bx = blockIdx.x*64, by = blockIdx.y*64;
        int c = tid&63;
        for (int r = tid>>6; r<64; r+=4) tile[r][c] = W[(size_t)(by+r)*512 + bx + c];
        __syncthreads();
        for (int n = tid>>6; n<64; n+=4) WT[(size_t)(bx+n)*512 + by + c] = (_Float16)tile[c][n];
    } else {
        int idx = blockIdx.y*8 + blockIdx.x;   // 0..63
        int i = (idx*256 + tid)*8;
        float4 a = *(const float4*)(Wc+i);
        float4 b2 = *(const float4*)(Wc+i+4);
        *(v8h*)(WcH+i) = cvt8(a,b2);
        if (idx == 0) zero[tid] = 0.f;
        if (idx == 1){ bcq[tid] = bq[tid]; bcq[tid+256] = bq[tid+256]; }
    }
}

// ---------------- bcq partial dots: bcq[j] += sum_{m in block} bc[m]*Wq[m][j]
__global__ __launch_bounds__(512) void k_bcqp(const float* __restrict__ bc,
                                              const float* __restrict__ Wq,
                                              float* __restrict__ bcq){
    int j = threadIdx.x; int m0 = blockIdx.x*16;
    float a = 0.f;
    #pragma unroll
    for (int m=0;m<16;m++) a += bc[m0+m]*Wq[(size_t)(m0+m)*512 + j];
    atomicAdd(&bcq[j], a);
}

// ---------------- GEMM v3: 128x128 tile, 512 thr, dbuf LDS + reg prefetch ----
template<typename AT, typename CT, bool QB>
__global__ __launch_bounds__(512) void k_gemm(const AT* __restrict__ A,
                                              const _Float16* __restrict__ WT,
                                              const float* __restrict__ bias,
                                              CT* __restrict__ C,
                                              int M, int N, int K,
                                              float scale,
                                              _Float16* __restrict__ qbT){
    __shared__ _Float16 Al[2][128*64];
    __shared__ _Float16 Wl[2][128*64];
    int tid = threadIdx.x, l = tid&63, w = tid>>6;
    int l15 = l&15, lq = l>>4;
    int wr = w>>2, wc = w&3;
    int m0 = blockIdx.y*128, n0 = blockIdx.x*128;
    v4f acc[4][2] = {};
    float bv[2];
    #pragma unroll
    for (int bc=0;bc<2;++bc) bv[bc] = bias[n0 + wc*32 + bc*16 + l15];
    int srow = tid>>2, sseg = (tid&3)*16;
    const AT* arow = A + (size_t)(m0+srow)*K + sseg;
    const _Float16* wrow = WT + (size_t)(n0+srow)*K + sseg;
    int NT = K>>6;

    v8h pa0, pa1, pw0, pw1;
    if constexpr (sizeof(AT)==4){
        const float* s = (const float*)arow;
        pa0 = cvt8(*(const float4*)s,     *(const float4*)(s+4));
        pa1 = cvt8(*(const float4*)(s+8), *(const float4*)(s+12));
    } else {
        pa0 = *(const v8h*)arow; pa1 = *(const v8h*)(arow+8);
    }
    pw0 = *(const v8h*)wrow; pw1 = *(const v8h*)(wrow+8);
    st8(&Al[0][swz(srow,sseg)], pa0); st8(&Al[0][swz(srow,sseg+8)], pa1);
    st8(&Wl[0][swz(srow,sseg)], pw0); st8(&Wl[0][swz(srow,sseg+8)], pw1);
    __syncthreads();

    for (int kt=0; kt<NT; ++kt){
        int cur = kt&1;
        if (kt < NT-1){
            int k0 = (kt+1)<<6;
            if constexpr (sizeof(AT)==4){
                const float* s = (const float*)arow + k0;
                pa0 = cvt8(*(const float4*)s,     *(const float4*)(s+4));
                pa1 = cvt8(*(const float4*)(s+8), *(const float4*)(s+12));
            } else {
                pa0 = *(const v8h*)(arow + k0); pa1 = *(const v8h*)(arow + k0 + 8);
            }
            pw0 = *(const v8h*)(wrow + k0); pw1 = *(const v8h*)(wrow + k0 + 8);
        }
        #pragma unroll
        for (int kk=0; kk<2; ++kk){
            v8h af[4], bf[2];
            #pragma unroll
            for (int ar=0;ar<4;++ar) af[ar] = *(v8h*)&Al[cur][swz(wr*64+ar*16+l15, kk*32+lq*8)];
            #pragma unroll
            for (int bc=0;bc<2;++bc) bf[bc] = *(v8h*)&Wl[cur][swz(wc*32+bc*16+l15, kk*32+lq*8)];
            #pragma unroll
            for (int ar=0;ar<4;++ar)
                #pragma unroll
                for (int bc=0;bc<2;++bc)
                    acc[ar][bc] = MFMA32(af[ar], bf[bc], acc[ar][bc]);
        }
        if (kt < NT-1){
            st8(&Al[cur^1][swz(srow,sseg)], pa0); st8(&Al[cur^1][swz(srow,sseg+8)], pa1);
            st8(&Wl[cur^1][swz(srow,sseg)], pw0); st8(&Wl[cur^1][swz(srow,sseg+8)], pw1);
        }
        __syncthreads();
    }
    #pragma unroll
    for (int ar=0;ar<4;++ar){
        #pragma unroll
        for (int bc=0;bc<2;++bc){
            #pragma unroll
            for (int i=0;i<4;++i){
                int row = m0 + wr*64 + ar*16 + lq*4 + i;
                int col = n0 + wc*32 + bc*16 + l15;
                float vf = (acc[ar][bc][i] + bv[bc])*scale;
                C[(size_t)row*N + col] = (CT)vf;
                if constexpr (QB){
                    int bI = row>>10, t = row&1023;
                    qbT[((size_t)t<<12) + (bI<<9) + col] = (_Float16)vf;
                }
            }
        }
    }
}

// ---------------- fused K+V projection v3: same structure, two W streams -----
__global__ __launch_bounds__(512) void k_gemmkv(const _Float16* __restrict__ A,
                                                const _Float16* __restrict__ WTk,
                                                const _Float16* __restrict__ WTv,
                                                const float* __restrict__ bk,
                                                const float* __restrict__ bv,
                                                _Float16* __restrict__ Ck,
                                                _Float16* __restrict__ Cv){
    __shared__ _Float16 Al[2][128*64];
    __shared__ _Float16 Wkl[2][128*64];
    __shared__ _Float16 Wvl[2][128*64];
    int tid = threadIdx.x, l = tid&63, w = tid>>6;
    int l15 = l&15, lq = l>>4;
    int wr = w>>2, wc = w&3;
    int m0 = blockIdx.y*128, n0 = blockIdx.x*128;
    v4f ack[4][2] = {}, acv[4][2] = {};
    float bkr[2], bvr[2];
    #pragma unroll
    for (int bc=0;bc<2;++bc){ bkr[bc] = bk[n0 + wc*32 + bc*16 + l15]; bvr[bc] = bv[n0 + wc*32 + bc*16 + l15]; }
    int srow = tid>>2, sseg = (tid&3)*16;
    const _Float16* arow = A   + (size_t)(m0+srow)*512 + sseg;
    const _Float16* krow = WTk + (size_t)(n0+srow)*512 + sseg;
    const _Float16* vrow = WTv + (size_t)(n0+srow)*512 + sseg;

    v8h pa0,pa1,pk0,pk1,pv0,pv1;
    pa0 = *(const v8h*)arow; pa1 = *(const v8h*)(arow+8);
    pk0 = *(const v8h*)krow; pk1 = *(const v8h*)(krow+8);
    pv0 = *(const v8h*)vrow; pv1 = *(const v8h*)(vrow+8);
    st8(&Al[0][swz(srow,sseg)],  pa0); st8(&Al[0][swz(srow,sseg+8)],  pa1);
    st8(&Wkl[0][swz(srow,sseg)], pk0); st8(&Wkl[0][swz(srow,sseg+8)], pk1);
    st8(&Wvl[0][swz(srow,sseg)], pv0); st8(&Wvl[0][swz(srow,sseg+8)], pv1);
    __syncthreads();

    for (int kt=0; kt<8; ++kt){
        int cur = kt&1;
        if (kt < 7){
            int k0 = (kt+1)<<6;
            pa0 = *(const v8h*)(arow+k0); pa1 = *(const v8h*)(arow+k0+8);
            pk0 = *(const v8h*)(krow+k0); pk1 = *(const v8h*)(krow+k0+8);
            pv0 = *(const v8h*)(vrow+k0); pv1 = *(const v8h*)(vrow+k0+8);
        }
        #pragma unroll
        for (int kk=0; kk<2; ++kk){
            v8h af[4], kf[2], vf[2];
            #pragma unroll
            for (int ar=0;ar<4;++ar) af[ar] = *(v8h*)&Al[cur][swz(wr*64+ar*16+l15, kk*32+lq*8)];
            #pragma unroll
            for (int bc=0;bc<2;++bc){
                kf[bc] = *(v8h*)&Wkl[cur][swz(wc*32+bc*16+l15, kk*32+lq*8)];
                vf[bc] = *(v8h*)&Wvl[cur][swz(wc*32+bc*16+l15, kk*32+lq*8)];
            }
            #pragma unroll
            for (int ar=0;ar<4;++ar)
                #pragma unroll
                for (int bc=0;bc<2;++bc){
                    ack[ar][bc] = MFMA32(af[ar], kf[bc], ack[ar][bc]);
                    acv[ar][bc] = MFMA32(af[ar], vf[bc], acv[ar][bc]);
                }
        }
        if (kt < 7){
            st8(&Al[cur^1][swz(srow,sseg)],  pa0); st8(&Al[cur^1][swz(srow,sseg+8)],  pa1);
            st8(&Wkl[cur^1][swz(srow,sseg)], pk0); st8(&Wkl[cur^1][swz(srow,sseg+8)], pk1);
            st8(&Wvl[cur^1][swz(srow,sseg)], pv0); st8(&Wvl[cur^1][swz(srow,sseg+8)], pv1);
        }
        __syncthreads();
    }
    #pragma unroll
    for (int ar=0;ar<4;++ar){
        #pragma unroll
        for (int bc=0;bc<2;++bc){
            #pragma unroll
            for (int i=0;i<4;++i){
                int row = m0 + wr*64 + ar*16 + lq*4 + i;
                int col = n0 + wc*32 + bc*16 + l15;
                Ck[(size_t)row*512 + col] = (_Float16)(ack[ar][bc][i] + bkr[bc]);
                Cv[(size_t)row*512 + col] = (_Float16)(acv[ar][bc][i] + bvr[bc]);
            }
        }
    }
}

// ---------------- bias v7: LDS double-buffer, 1 barrier per chunk ------------
__global__ __launch_bounds__(256) void k_bias(const _Float16* __restrict__ qb,
                                              const float* __restrict__ posk,
                                              const int* __restrict__ mask,
                                              _Float16* __restrict__ Sb){
    __shared__ _Float16 Pl[2][64*64];   // posk chunk [s][d] fp16, swizzled
    __shared__ _Float16 Ol[2][64*72];   // out tile [bh][s], pad 72
    int t = blockIdx.x >> 1, sh = blockIdx.x & 1;
    int tid = threadIdx.x, l = tid&63, w = tid>>6;
    int l31 = l&31, hi = l>>5;
    int g = w & 1, sg = w >> 1;      // wave's bh-group / s-subgroup
    v8h aa[4];
    const _Float16* qbt = qb + ((size_t)t<<12);
    #pragma unroll
    for (int k0=0;k0<4;++k0)
        aa[k0] = *(const v8h*)(qbt + (g*32 + l31)*64 + k0*16 + hi*8);

    const float* pkt = posk + ((size_t)t<<16);
    int sbase = sh*512;
    int lrow = (l>>4), lcol = (l&15)*4;      // within-wave load geometry

    v4f pf[4];
    #pragma unroll
    for (int j=0;j<4;++j)
        pf[j] = *(const v4f*)(pkt + (size_t)(sbase + w*16 + j*4 + lrow)*64 + lcol);

    int obh = tid>>2;
    int osl = (tid&3)*16;
    int ob  = obh>>3;
    const int* mbase = mask + (((size_t)(ob*Tt + t))<<10);
    _Float16* sbb = Sb + (((size_t)(t*64 + obh))<<10);

    // write chunk0 to Pl[0]
    #pragma unroll
    for (int j=0;j<4;++j){
        v4h hv; hv[0]=(_Float16)pf[j][0]; hv[1]=(_Float16)pf[j][1];
                hv[2]=(_Float16)pf[j][2]; hv[3]=(_Float16)pf[j][3];
        *(v4h*)&Pl[0][swz(w*16 + j*4 + lrow, lcol)] = hv;
    }
    __syncthreads();

    for (int sc=0; sc<8; ++sc){
        int cur = sc&1;
        int s0 = sbase + sc*64;
        if (sc < 7){
            #pragma unroll
            for (int j=0;j<4;++j)
                pf[j] = *(const v4f*)(pkt + (size_t)(s0 + 64 + w*16 + j*4 + lrow)*64 + lcol);
        }
        int4 mq[4];
        #pragma unroll
        for (int j=0;j<4;++j)
            mq[j] = *(const int4*)(mbase + s0 + osl + j*4);
        v8h bfr[4];
        #pragma unroll
        for (int k0=0;k0<4;++k0)
            bfr[k0] = *(v8h*)&Pl[cur][swz(sg*32 + l31, k0*16 + hi*8)];
        v16f acc = {};
        #pragma unroll
        for (int k0=0;k0<4;++k0) acc = MFMA3216(aa[k0], bfr[k0], acc);
        #pragma unroll
        for (int r=0;r<16;++r){
            int bh = g*32 + (r&3) + 4*hi + 8*(r>>2);
            Ol[cur][bh*72 + sg*32 + l31] = (_Float16)acc[r];
        }
        if (sc < 7){
            #pragma unroll
            for (int j=0;j<4;++j){
                v4h hv; hv[0]=(_Float16)pf[j][0]; hv[1]=(_Float16)pf[j][1];
                        hv[2]=(_Float16)pf[j][2]; hv[3]=(_Float16)pf[j][3];
                *(v4h*)&Pl[cur^1][swz(w*16 + j*4 + lrow, lcol)] = hv;
            }
        }
        __syncthreads();
        v8h o0 = *(v8h*)&Ol[cur][obh*72 + osl];
        v8h o1 = *(v8h*)&Ol[cur][obh*72 + osl + 8];
        const _Float16 NEG = (_Float16)(-30000.f);
        int mm[16] = {mq[0].x,mq[0].y,mq[0].z,mq[0].w, mq[1].x,mq[1].y,mq[1].z,mq[1].w,
                      mq[2].x,mq[2].y,mq[2].z,mq[2].w, mq[3].x,mq[3].y,mq[3].z,mq[3].w};
        #pragma unroll
        for (int j=0;j<8;++j){ if(!mm[j]) o0[j]=NEG; if(!mm[8+j]) o1[j]=NEG; }
        *(v8h*)(sbb + s0 + osl)     = o0;
        *(v8h*)(sbb + s0 + osl + 8) = o1;
    }
}

// ---------------- flash v5: register bias + wave-private P, dbuf K/V only ----
// grid (64 bh, 8 t-tiles of 128), 512 thr. LDS 48 KB -> 3 blocks/CU.
__global__ __launch_bounds__(512) void k_flash(const _Float16* __restrict__ qs,
                                               const _Float16* __restrict__ kbuf,
                                               const _Float16* __restrict__ vbuf,
                                               const _Float16* __restrict__ Sb,
                                               _Float16* __restrict__ ao){
    __shared__ _Float16 Kl[2][64*64];    // [s][d] swizzled (shared across waves)
    __shared__ _Float16 Vt[2][64*64];    // [d][s] swizzled (shared across waves)
    __shared__ _Float16 Pw[128*64];      // P, wave-private rows: NO barrier needed
    int bh = blockIdx.x; int b = bh>>3, h = bh&7;
    int t0 = blockIdx.y*128;
    int tid = threadIdx.x, l = tid&63, w = tid>>6, l15 = l&15, lq = l>>4;

    v8h qa[2];
    #pragma unroll
    for (int u=0;u<2;++u)
        qa[u] = *(const v8h*)(qs + ((size_t)(b*Tt + t0 + w*16 + l15))*NFf + h*DKk + u*32 + lq*8);

    v4f O[4] = {};
    float m_l = -1e30f, l_l = 0.f;

    int kr = tid>>3, kseg = (tid&7)*8;
    int vs = tid&63, vd0 = (tid>>6)*8;
    const _Float16* kbase = kbuf + ((size_t)(b*Tt + kr))*NFf + h*DKk + kseg;
    const _Float16* vbase = vbuf + ((size_t)(b*Tt + vs))*NFf + h*DKk + vd0;
    // per-lane bias pointer: row t = t0 + w*16 + l15, cols s0 + nt*16 + lq*4
    const _Float16* sbL = Sb + (((size_t)((t0 + w*16 + l15)*64 + bh))<<10);

    // prefetch + stage chunk 0
    v8h pk = *(const v8h*)kbase;
    v8h pv = *(const v8h*)vbase;
    v4h pb[4];
    #pragma unroll
    for (int nt=0;nt<4;++nt) pb[nt] = *(const v4h*)(sbL + nt*16 + lq*4);
    st8(&Kl[0][swz(kr, kseg)], pk);
    #pragma unroll
    for (int j=0;j<8;j++) Vt[0][swz(vd0+j, vs)] = pv[j];
    __syncthreads();

    for (int sc=0; sc<16; ++sc){
        int cur = sc&1;
        // issue next chunk's global loads (land during compute)
        v4h pbn[4];
        if (sc < 15){
            size_t soff = (size_t)(sc+1)*64;
            pk  = *(const v8h*)(kbase + soff*NFf);
            pv  = *(const v8h*)(vbase + soff*NFf);
            #pragma unroll
            for (int nt=0;nt<4;++nt) pbn[nt] = *(const v4h*)(sbL + soff + nt*16 + lq*4);
        }

        // QK^T swapped from Kl[cur]: col = t (l15), row = s; bias from regs
        v4f sv[4];
        #pragma unroll
        for (int nt=0; nt<4; ++nt){
            v8h kb0 = *(v8h*)&Kl[cur][swz(nt*16+l15, lq*8)];
            v8h kb1 = *(v8h*)&Kl[cur][swz(nt*16+l15, 32+lq*8)];
            v4f a = {};
            a = MFMA32(kb0, qa[0], a);
            a = MFMA32(kb1, qa[1], a);
            #pragma unroll
            for (int i=0;i<4;i++) a[i] += (float)pb[nt][i];
            sv[nt] = a;
        }
        float mx = fmaxf(fmaxf(fmaxf(sv[0][0],sv[0][1]),fmaxf(sv[0][2],sv[0][3])),
                   fmaxf(fmaxf(fmaxf(sv[1][0],sv[1][1]),fmaxf(sv[1][2],sv[1][3])),
                   fmaxf(fmaxf(fmaxf(sv[2][0],sv[2][1]),fmaxf(sv[2][2],sv[2][3])),
                         fmaxf(fmaxf(sv[3][0],sv[3][1]),fmaxf(sv[3][2],sv[3][3])))));
        mx = fmaxf(mx, __shfl_xor(mx,16));
        mx = fmaxf(mx, __shfl_xor(mx,32));
        float mn = fmaxf(m_l, mx);
        if (__any(mn - m_l > 0.f)){
            float rsc = exp2f(m_l - mn);
            m_l = mn; l_l *= rsc;
            float rscB[4];
            #pragma unroll
            for (int i=0;i<4;i++) rscB[i] = __shfl(rsc, lq*4+i);
            #pragma unroll
            for (int nt=0; nt<4; ++nt)
                #pragma unroll
                for (int i=0;i<4;i++) O[nt][i] *= rscB[i];
        }
        float ps = 0.f;
        #pragma unroll
        for (int nt=0; nt<4; ++nt){
            v4h ph;
            #pragma unroll
            for (int i=0;i<4;i++){
                float p = exp2f(sv[nt][i] - m_l);
                ph[i] = (_Float16)p;
                ps += p;
            }
            *(v4h*)&Pw[swz(w*16 + l15, nt*16 + lq*4)] = ph;   // wave-private rows
        }
        ps += __shfl_xor(ps,16);
        ps += __shfl_xor(ps,32);
        l_l += ps;
        // PV: A = P rows (own wave, no barrier), B = Vt[cur]
        {
            v8h pa0 = *(v8h*)&Pw[swz(w*16+l15, lq*8)];
            v8h pa1 = *(v8h*)&Pw[swz(w*16+l15, 32+lq*8)];
            #pragma unroll
            for (int nt=0; nt<4; ++nt){
                v8h vb0 = *(v8h*)&Vt[cur][swz(nt*16+l15, lq*8)];
                v8h vb1 = *(v8h*)&Vt[cur][swz(nt*16+l15, 32+lq*8)];
                O[nt] = MFMA32(pa0, vb0, O[nt]);
                O[nt] = MFMA32(pa1, vb1, O[nt]);
            }
        }
        // write staged chunk sc+1 into K/V buf[cur^1]
        if (sc < 15){
            st8(&Kl[cur^1][swz(kr, kseg)], pk);
            #pragma unroll
            for (int j=0;j<8;j++) Vt[cur^1][swz(vd0+j, vs)] = pv[j];
            #pragma unroll
            for (int nt=0;nt<4;++nt) pb[nt] = pbn[nt];
        }
        __syncthreads();
    }

    float rl = (l_l > 0.f) ? 1.f/l_l : 0.f;
    float rlB[4];
    #pragma unroll
    for (int i=0;i<4;i++) rlB[i] = __shfl(rl, lq*4+i);
    #pragma unroll
    for (int i=0;i<4;i++){
        int row = t0 + w*16 + lq*4 + i;
        #pragma unroll
        for (int nt=0; nt<4; ++nt)
            ao[((size_t)(b*Tt + row))*NFf + h*DKk + nt*16 + l15] = (_Float16)(O[nt][i]*rlB[i]);
    }
}

// ---------------- launch ----------------
extern "C" void kernel_launch(void* const* d_in, const int* in_sizes, int n_in,
                              void* d_out, int out_size, void* d_ws, size_t ws_size,
                              hipStream_t stream) {
    const float* x       = (const float*)d_in[0];
    const float* cond    = (const float*)d_in[1];
    const float* pos_k   = (const float*)d_in[2];
    const int*   mask    = (const int*)  d_in[3];
    const float* ln_g    = (const float*)d_in[4];
    const float* ln_b    = (const float*)d_in[5];
    const float* Wq      = (const float*)d_in[6];
    const float* bq      = (const float*)d_in[7];
    const float* Wk      = (const float*)d_in[8];
    const float* bk      = (const float*)d_in[9];
    const float* Wv      = (const float*)d_in[10];
    const float* bv      = (const float*)d_in[11];
    const float* Wo      = (const float*)d_in[12];
    const float* bo      = (const float*)d_in[13];
    const float* Wc      = (const float*)d_in[14];
    const float* bc      = (const float*)d_in[15];
    float* out = (float*)d_out;

    char* base = (char*)d_ws;
    const size_t OFF_S    = 0;                       // 134217728 B fp16 Sb
    const size_t OFF_XN   = 134217728;
    const size_t OFF_Q    = OFF_XN  + 8388608;
    const size_t OFF_QB   = OFF_Q   + 8388608;
    const size_t OFF_K    = OFF_QB  + 8388608;
    const size_t OFF_V    = OFF_K   + 8388608;
    const size_t OFF_AO   = OFF_V   + 8388608;
    const size_t OFF_WKT  = OFF_AO  + 8388608;       // 524288
    const size_t OFF_WVT  = OFF_WKT + 524288;
    const size_t OFF_WOT  = OFF_WVT + 524288;
    const size_t OFF_WQT  = OFF_WOT + 524288;        // 524288
    const size_t OFF_WCH  = OFF_WQT + 524288;        // 262144
    const size_t OFF_WCQT = OFF_WCH + 262144;        // 262144
    const size_t OFF_BCQ  = OFF_WCQT + 262144;       // 2048
    const size_t OFF_ZERO = OFF_BCQ + 2048;          // 1024

    _Float16* xn    = (_Float16*)(base + OFF_XN);
    _Float16* qbuf  = (_Float16*)(base + OFF_Q);
    _Float16* qb    = (_Float16*)(base + OFF_QB);
    _Float16* kb    = (_Float16*)(base + OFF_K);
    _Float16* vb    = (_Float16*)(base + OFF_V);
    _Float16* ao    = (_Float16*)(base + OFF_AO);
    _Float16* Sb    = (_Float16*)(base + OFF_S);
    _Float16* WkT   = (_Float16*)(base + OFF_WKT);
    _Float16* WvT   = (_Float16*)(base + OFF_WVT);
    _Float16* WoT   = (_Float16*)(base + OFF_WOT);
    _Float16* WqT   = (_Float16*)(base + OFF_WQT);
    _Float16* WcH   = (_Float16*)(base + OFF_WCH);
    _Float16* wcqT  = (_Float16*)(base + OFF_WCQT);
    float*    bcq   = (float*)(base + OFF_BCQ);
    float*    zero  = (float*)(base + OFF_ZERO);

    k_ln<<<dim3(Bb*Tt), dim3(256), 0, stream>>>(x, ln_g, ln_b, xn);
    k_prep<<<dim3(8,8,5), dim3(256), 0, stream>>>(Wk, Wv, Wo, Wq, WkT, WvT, WoT, WqT, Wc, WcH, bq, bcq, zero);
    k_bcqp<<<dim3(16), dim3(512), 0, stream>>>(bc, Wq, bcq);

    // wcqT(512x256) = WqT(512x512) @ WcH(256x512)^T  via GEMM v3
    k_gemm<_Float16,_Float16,false><<<dim3(2,4), dim3(512), 0, stream>>>(WqT, WcH, zero, wcqT, 512, 256, 512, 1.f, nullptr);

    // q projection: writes scaled qbuf AND scaled transposed qb
    k_gemm<float,_Float16,true><<<dim3(4,64), dim3(512), 0, stream>>>(cond, wcqT, bcq, qbuf, Bb*Tt, 512, 256, SCQ, qb);
    // fused K+V projection
    k_gemmkv<<<dim3(4,64), dim3(512), 0, stream>>>(xn, WkT, WvT, bk, bv, kb, vb);

    k_bias<<<dim3(2048), dim3(256), 0, stream>>>(qb, pos_k, mask, Sb);
    k_flash<<<dim3(64,8), dim3(512), 0, stream>>>(qbuf, kb, vb, Sb, ao);

    k_gemm<_Float16,float,false><<<dim3(4,64), dim3(512), 0, stream>>>(ao, WoT, bo, out, Bb*Tt, 512, 512, 1.f, nullptr);
}

// Round 17
// 208.719 us; speedup vs baseline: 1.0725x; 1.0725x over previous
//
#include <hip/hip_runtime.h>

// ---------------- problem constants ----------------
#define Bb 8
#define Tt 1024
#define Hh 8
#define DKk 64
#define NFf 512
#define DCc 256

typedef _Float16 v2h __attribute__((ext_vector_type(2)));
typedef _Float16 v4h __attribute__((ext_vector_type(4)));
typedef _Float16 v8h __attribute__((ext_vector_type(8)));
typedef float    v4f __attribute__((ext_vector_type(4)));
typedef float    v16f __attribute__((ext_vector_type(16)));

#define MFMA32(a,b,c) __builtin_amdgcn_mfma_f32_16x16x32_f16((a),(b),(c),0,0,0)
#define MFMA3216(a,b,c) __builtin_amdgcn_mfma_f32_32x32x16_f16((a),(b),(c),0,0,0)

// scale folded into q: 1/sqrt(64) * log2(e)  (scores live in log2 domain)
#define SCQ 0.1803368801111f

__device__ inline void st8(_Float16* dst, v8h x){
    *(v4h*)dst     = __builtin_shufflevector(x,x,0,1,2,3);
    *(v4h*)(dst+4) = __builtin_shufflevector(x,x,4,5,6,7);
}

__device__ inline v8h cvt8(float4 a, float4 b){
    v8h r;
    r[0]=(_Float16)a.x; r[1]=(_Float16)a.y; r[2]=(_Float16)a.z; r[3]=(_Float16)a.w;
    r[4]=(_Float16)b.x; r[5]=(_Float16)b.y; r[6]=(_Float16)b.z; r[7]=(_Float16)b.w;
    return r;
}

// XOR swizzle for [R][64] half LDS tiles; keeps 8-half granularity
__device__ inline int swz(int r, int c){ return (r*64 + c) ^ ((r&7)<<3); }

// ---------------- front: [0,320) weight prep ; [320,8512) LayerNorm ----------
__global__ __launch_bounds__(256) void k_front(const float* __restrict__ x,
                                               const float* __restrict__ g,
                                               const float* __restrict__ be,
                                               _Float16* __restrict__ xn,
                                               const float* __restrict__ Wk,
                                               const float* __restrict__ Wv,
                                               const float* __restrict__ Wo,
                                               const float* __restrict__ Wq,
                                               _Float16* __restrict__ WkT,
                                               _Float16* __restrict__ WvT,
                                               _Float16* __restrict__ WoT,
                                               _Float16* __restrict__ WqT,
                                               const float* __restrict__ Wc,
                                               _Float16* __restrict__ WcH,
                                               const float* __restrict__ bq,
                                               float* __restrict__ bcq,
                                               float* __restrict__ zero){
    __shared__ float smem[64*65];
    int bid = blockIdx.x;
    int tid = threadIdx.x;
    if (bid < 320){
        int z = bid >> 6;          // 0..4
        int xy = bid & 63;
        if (z < 4){
            const float* W = (z==0)?Wk:(z==1)?Wv:(z==2)?Wo:Wq;
            _Float16*  WT = (z==0)?WkT:(z==1)?WvT:(z==2)?WoT:WqT;
            int bx = (xy&7)*64, by = (xy>>3)*64;
            int c = tid&63;
            float (*tile)[65] = (float(*)[65])smem;
            for (int r = tid>>6; r<64; r+=4) tile[r][c] = W[(size_t)(by+r)*512 + bx + c];
            __syncthreads();
            for (int n = tid>>6; n<64; n+=4) WT[(size_t)(bx+n)*512 + by + c] = (_Float16)tile[c][n];
        } else {
            int i = (xy*256 + tid)*8;
            float4 a = *(const float4*)(Wc+i);
            float4 b2 = *(const float4*)(Wc+i+4);
            *(v8h*)(WcH+i) = cvt8(a,b2);
            if (xy == 0) zero[tid] = 0.f;
            if (xy == 1){ bcq[tid] = bq[tid]; bcq[tid+256] = bq[tid+256]; }
        }
        return;
    }
    // LayerNorm
    int row = bid - 320;
    const float* xr = x + (size_t)row*512;
    float2 v = reinterpret_cast<const float2*>(xr)[tid];
    float s = v.x + v.y, sq = v.x*v.x + v.y*v.y;
    for (int off=32; off; off>>=1){ s += __shfl_down(s, off); sq += __shfl_down(sq, off); }
    int wid = tid>>6, lid = tid&63;
    if (lid==0){ smem[wid]=s; smem[4+wid]=sq; }
    __syncthreads();
    if (tid==0){
        float S=0,Q=0;
        for(int i=0;i<4;i++){S+=smem[i];Q+=smem[4+i];}
        float mu = S*(1.f/512.f);
        float var = Q*(1.f/512.f)-mu*mu;
        smem[8]=mu; smem[9]=rsqrtf(var+1e-5f);
    }
    __syncthreads();
    float mu=smem[8], rs=smem[9];
    float2 gv = reinterpret_cast<const float2*>(g)[tid];
    float2 bv = reinterpret_cast<const float2*>(be)[tid];
    v2h o; o[0] = (_Float16)((v.x-mu)*rs*gv.x + bv.x);
           o[1] = (_Float16)((v.y-mu)*rs*gv.y + bv.y);
    reinterpret_cast<v2h*>(xn + (size_t)row*512)[tid] = o;
}

// ---------------- bcq partial dots: bcq[j] += sum_{m in block} bc[m]*Wq[m][j]
__global__ __launch_bounds__(512) void k_bcqp(const float* __restrict__ bc,
                                              const float* __restrict__ Wq,
                                              float* __restrict__ bcq){
    int j = threadIdx.x; int m0 = blockIdx.x*16;
    float a = 0.f;
    #pragma unroll
    for (int m=0;m<16;m++) a += bc[m0+m]*Wq[(size_t)(m0+m)*512 + j];
    atomicAdd(&bcq[j], a);
}

// ---------------- GEMM v3: 128x128 tile, 512 thr, dbuf LDS + reg prefetch ----
template<typename AT, typename CT, bool QB>
__global__ __launch_bounds__(512) void k_gemm(const AT* __restrict__ A,
                                              const _Float16* __restrict__ WT,
                                              const float* __restrict__ bias,
                                              CT* __restrict__ C,
                                              int M, int N, int K,
                                              float scale,
                                              _Float16* __restrict__ qbT){
    __shared__ _Float16 Al[2][128*64];
    __shared__ _Float16 Wl[2][128*64];
    int tid = threadIdx.x, l = tid&63, w = tid>>6;
    int l15 = l&15, lq = l>>4;
    int wr = w>>2, wc = w&3;
    int m0 = blockIdx.y*128, n0 = blockIdx.x*128;
    v4f acc[4][2] = {};
    float bv[2];
    #pragma unroll
    for (int bc=0;bc<2;++bc) bv[bc] = bias[n0 + wc*32 + bc*16 + l15];
    int srow = tid>>2, sseg = (tid&3)*16;
    const AT* arow = A + (size_t)(m0+srow)*K + sseg;
    const _Float16* wrow = WT + (size_t)(n0+srow)*K + sseg;
    int NT = K>>6;

    v8h pa0, pa1, pw0, pw1;
    if constexpr (sizeof(AT)==4){
        const float* s = (const float*)arow;
        pa0 = cvt8(*(const float4*)s,     *(const float4*)(s+4));
        pa1 = cvt8(*(const float4*)(s+8), *(const float4*)(s+12));
    } else {
        pa0 = *(const v8h*)arow; pa1 = *(const v8h*)(arow+8);
    }
    pw0 = *(const v8h*)wrow; pw1 = *(const v8h*)(wrow+8);
    st8(&Al[0][swz(srow,sseg)], pa0); st8(&Al[0][swz(srow,sseg+8)], pa1);
    st8(&Wl[0][swz(srow,sseg)], pw0); st8(&Wl[0][swz(srow,sseg+8)], pw1);
    __syncthreads();

    for (int kt=0; kt<NT; ++kt){
        int cur = kt&1;
        if (kt < NT-1){
            int k0 = (kt+1)<<6;
            if constexpr (sizeof(AT)==4){
                const float* s = (const float*)arow + k0;
                pa0 = cvt8(*(const float4*)s,     *(const float4*)(s+4));
                pa1 = cvt8(*(const float4*)(s+8), *(const float4*)(s+12));
            } else {
                pa0 = *(const v8h*)(arow + k0); pa1 = *(const v8h*)(arow + k0 + 8);
            }
            pw0 = *(const v8h*)(wrow + k0); pw1 = *(const v8h*)(wrow + k0 + 8);
        }
        #pragma unroll
        for (int kk=0; kk<2; ++kk){
            v8h af[4], bf[2];
            #pragma unroll
            for (int ar=0;ar<4;++ar) af[ar] = *(v8h*)&Al[cur][swz(wr*64+ar*16+l15, kk*32+lq*8)];
            #pragma unroll
            for (int bc=0;bc<2;++bc) bf[bc] = *(v8h*)&Wl[cur][swz(wc*32+bc*16+l15, kk*32+lq*8)];
            #pragma unroll
            for (int ar=0;ar<4;++ar)
                #pragma unroll
                for (int bc=0;bc<2;++bc)
                    acc[ar][bc] = MFMA32(af[ar], bf[bc], acc[ar][bc]);
        }
        if (kt < NT-1){
            st8(&Al[cur^1][swz(srow,sseg)], pa0); st8(&Al[cur^1][swz(srow,sseg+8)], pa1);
            st8(&Wl[cur^1][swz(srow,sseg)], pw0); st8(&Wl[cur^1][swz(srow,sseg+8)], pw1);
        }
        __syncthreads();
    }
    #pragma unroll
    for (int ar=0;ar<4;++ar){
        #pragma unroll
        for (int bc=0;bc<2;++bc){
            #pragma unroll
            for (int i=0;i<4;++i){
                int row = m0 + wr*64 + ar*16 + lq*4 + i;
                int col = n0 + wc*32 + bc*16 + l15;
                float vf = (acc[ar][bc][i] + bv[bc])*scale;
                C[(size_t)row*N + col] = (CT)vf;
                if constexpr (QB){
                    int bI = row>>10, t = row&1023;
                    qbT[((size_t)t<<12) + (bI<<9) + col] = (_Float16)vf;
                }
            }
        }
    }
}

// ---------------- fused K+V projection v3: same structure, two W streams -----
__global__ __launch_bounds__(512) void k_gemmkv(const _Float16* __restrict__ A,
                                                const _Float16* __restrict__ WTk,
                                                const _Float16* __restrict__ WTv,
                                                const float* __restrict__ bk,
                                                const float* __restrict__ bv,
                                                _Float16* __restrict__ Ck,
                                                _Float16* __restrict__ Cv){
    __shared__ _Float16 Al[2][128*64];
    __shared__ _Float16 Wkl[2][128*64];
    __shared__ _Float16 Wvl[2][128*64];
    int tid = threadIdx.x, l = tid&63, w = tid>>6;
    int l15 = l&15, lq = l>>4;
    int wr = w>>2, wc = w&3;
    int m0 = blockIdx.y*128, n0 = blockIdx.x*128;
    v4f ack[4][2] = {}, acv[4][2] = {};
    float bkr[2], bvr[2];
    #pragma unroll
    for (int bc=0;bc<2;++bc){ bkr[bc] = bk[n0 + wc*32 + bc*16 + l15]; bvr[bc] = bv[n0 + wc*32 + bc*16 + l15]; }
    int srow = tid>>2, sseg = (tid&3)*16;
    const _Float16* arow = A   + (size_t)(m0+srow)*512 + sseg;
    const _Float16* krow = WTk + (size_t)(n0+srow)*512 + sseg;
    const _Float16* vrow = WTv + (size_t)(n0+srow)*512 + sseg;

    v8h pa0,pa1,pk0,pk1,pv0,pv1;
    pa0 = *(const v8h*)arow; pa1 = *(const v8h*)(arow+8);
    pk0 = *(const v8h*)krow; pk1 = *(const v8h*)(krow+8);
    pv0 = *(const v8h*)vrow; pv1 = *(const v8h*)(vrow+8);
    st8(&Al[0][swz(srow,sseg)],  pa0); st8(&Al[0][swz(srow,sseg+8)],  pa1);
    st8(&Wkl[0][swz(srow,sseg)], pk0); st8(&Wkl[0][swz(srow,sseg+8)], pk1);
    st8(&Wvl[0][swz(srow,sseg)], pv0); st8(&Wvl[0][swz(srow,sseg+8)], pv1);
    __syncthreads();

    for (int kt=0; kt<8; ++kt){
        int cur = kt&1;
        if (kt < 7){
            int k0 = (kt+1)<<6;
            pa0 = *(const v8h*)(arow+k0); pa1 = *(const v8h*)(arow+k0+8);
            pk0 = *(const v8h*)(krow+k0); pk1 = *(const v8h*)(krow+k0+8);
            pv0 = *(const v8h*)(vrow+k0); pv1 = *(const v8h*)(vrow+k0+8);
        }
        #pragma unroll
        for (int kk=0; kk<2; ++kk){
            v8h af[4], kf[2], vf[2];
            #pragma unroll
            for (int ar=0;ar<4;++ar) af[ar] = *(v8h*)&Al[cur][swz(wr*64+ar*16+l15, kk*32+lq*8)];
            #pragma unroll
            for (int bc=0;bc<2;++bc){
                kf[bc] = *(v8h*)&Wkl[cur][swz(wc*32+bc*16+l15, kk*32+lq*8)];
                vf[bc] = *(v8h*)&Wvl[cur][swz(wc*32+bc*16+l15, kk*32+lq*8)];
            }
            #pragma unroll
            for (int ar=0;ar<4;++ar)
                #pragma unroll
                for (int bc=0;bc<2;++bc){
                    ack[ar][bc] = MFMA32(af[ar], kf[bc], ack[ar][bc]);
                    acv[ar][bc] = MFMA32(af[ar], vf[bc], acv[ar][bc]);
                }
        }
        if (kt < 7){
            st8(&Al[cur^1][swz(srow,sseg)],  pa0); st8(&Al[cur^1][swz(srow,sseg+8)],  pa1);
            st8(&Wkl[cur^1][swz(srow,sseg)], pk0); st8(&Wkl[cur^1][swz(srow,sseg+8)], pk1);
            st8(&Wvl[cur^1][swz(srow,sseg)], pv0); st8(&Wvl[cur^1][swz(srow,sseg+8)], pv1);
        }
        __syncthreads();
    }
    #pragma unroll
    for (int ar=0;ar<4;++ar){
        #pragma unroll
        for (int bc=0;bc<2;++bc){
            #pragma unroll
            for (int i=0;i<4;++i){
                int row = m0 + wr*64 + ar*16 + lq*4 + i;
                int col = n0 + wc*32 + bc*16 + l15;
                Ck[(size_t)row*512 + col] = (_Float16)(ack[ar][bc][i] + bkr[bc]);
                Cv[(size_t)row*512 + col] = (_Float16)(acv[ar][bc][i] + bvr[bc]);
            }
        }
    }
}

// ---------------- bias v8: single Pl + single Ol, 2 barriers, 17 KB LDS ------
// 8 blocks/CU (32 waves). Race audit: Pl reads before barrier-A, Pl writes
// after A, next reads after B; Ol writes before A, reads between A/B, next
// writes after B.
__global__ __launch_bounds__(256) void k_bias(const _Float16* __restrict__ qb,
                                              const float* __restrict__ posk,
                                              const int* __restrict__ mask,
                                              _Float16* __restrict__ Sb){
    __shared__ _Float16 Pl[64*64];   // posk chunk [s][d] fp16, swizzled
    __shared__ _Float16 Ol[64*72];   // out tile [bh][s], pad 72
    int t = blockIdx.x >> 1, sh = blockIdx.x & 1;
    int tid = threadIdx.x, l = tid&63, w = tid>>6;
    int l31 = l&31, hi = l>>5;
    int g = w & 1, sg = w >> 1;      // wave's bh-group / s-subgroup
    v8h aa[4];
    const _Float16* qbt = qb + ((size_t)t<<12);
    #pragma unroll
    for (int k0=0;k0<4;++k0)
        aa[k0] = *(const v8h*)(qbt + (g*32 + l31)*64 + k0*16 + hi*8);

    const float* pkt = posk + ((size_t)t<<16);
    int sbase = sh*512;
    int lrow = (l>>4), lcol = (l&15)*4;      // within-wave load geometry

    v4f pf[4];
    #pragma unroll
    for (int j=0;j<4;++j)
        pf[j] = *(const v4f*)(pkt + (size_t)(sbase + w*16 + j*4 + lrow)*64 + lcol);

    int obh = tid>>2;
    int osl = (tid&3)*16;
    int ob  = obh>>3;
    const int* mbase = mask + (((size_t)(ob*Tt + t))<<10);
    _Float16* sbb = Sb + (((size_t)(t*64 + obh))<<10);

    // stage chunk0
    #pragma unroll
    for (int j=0;j<4;++j){
        v4h hv; hv[0]=(_Float16)pf[j][0]; hv[1]=(_Float16)pf[j][1];
                hv[2]=(_Float16)pf[j][2]; hv[3]=(_Float16)pf[j][3];
        *(v4h*)&Pl[swz(w*16 + j*4 + lrow, lcol)] = hv;
    }
    __syncthreads();

    for (int sc=0; sc<8; ++sc){
        int s0 = sbase + sc*64;
        if (sc < 7){
            #pragma unroll
            for (int j=0;j<4;++j)
                pf[j] = *(const v4f*)(pkt + (size_t)(s0 + 64 + w*16 + j*4 + lrow)*64 + lcol);
        }
        int4 mq[4];
        #pragma unroll
        for (int j=0;j<4;++j)
            mq[j] = *(const int4*)(mbase + s0 + osl + j*4);
        v8h bfr[4];
        #pragma unroll
        for (int k0=0;k0<4;++k0)
            bfr[k0] = *(v8h*)&Pl[swz(sg*32 + l31, k0*16 + hi*8)];
        v16f acc = {};
        #pragma unroll
        for (int k0=0;k0<4;++k0) acc = MFMA3216(aa[k0], bfr[k0], acc);
        #pragma unroll
        for (int r=0;r<16;++r){
            int bh = g*32 + (r&3) + 4*hi + 8*(r>>2);
            Ol[bh*72 + sg*32 + l31] = (_Float16)acc[r];
        }
        __syncthreads();   // A: Pl reads + Ol writes complete
        if (sc < 7){
            #pragma unroll
            for (int j=0;j<4;++j){
                v4h hv; hv[0]=(_Float16)pf[j][0]; hv[1]=(_Float16)pf[j][1];
                        hv[2]=(_Float16)pf[j][2]; hv[3]=(_Float16)pf[j][3];
                *(v4h*)&Pl[swz(w*16 + j*4 + lrow, lcol)] = hv;
            }
        }
        v8h o0 = *(v8h*)&Ol[obh*72 + osl];
        v8h o1 = *(v8h*)&Ol[obh*72 + osl + 8];
        const _Float16 NEG = (_Float16)(-30000.f);
        int mm[16] = {mq[0].x,mq[0].y,mq[0].z,mq[0].w, mq[1].x,mq[1].y,mq[1].z,mq[1].w,
                      mq[2].x,mq[2].y,mq[2].z,mq[2].w, mq[3].x,mq[3].y,mq[3].z,mq[3].w};
        #pragma unroll
        for (int j=0;j<8;++j){ if(!mm[j]) o0[j]=NEG; if(!mm[8+j]) o1[j]=NEG; }
        *(v8h*)(sbb + s0 + osl)     = o0;
        *(v8h*)(sbb + s0 + osl + 8) = o1;
        __syncthreads();   // B: Ol reads + Pl writes complete
    }
}

// ---------------- flash v4 (round-15): swapped QK + dbuf LDS, 1 barrier/chunk
__global__ __launch_bounds__(512) void k_flash(const _Float16* __restrict__ qs,
                                               const _Float16* __restrict__ kbuf,
                                               const _Float16* __restrict__ vbuf,
                                               const _Float16* __restrict__ Sb,
                                               _Float16* __restrict__ ao){
    __shared__ _Float16 Kl[2][64*64];    // [s][d] swizzled
    __shared__ _Float16 Vt[2][64*64];    // [d][s] swizzled
    __shared__ _Float16 Bl[2][128*64];   // bias chunk then P (wave-private rows)
    int bh = blockIdx.x; int b = bh>>3, h = bh&7;
    int t0 = blockIdx.y*128;
    int tid = threadIdx.x, l = tid&63, w = tid>>6, l15 = l&15, lq = l>>4;

    v8h qa[2];
    #pragma unroll
    for (int u=0;u<2;++u)
        qa[u] = *(const v8h*)(qs + ((size_t)(b*Tt + t0 + w*16 + l15))*NFf + h*DKk + u*32 + lq*8);

    v4f O[4] = {};
    float m_l = -1e30f, l_l = 0.f;

    int kr = tid>>3, kseg = (tid&7)*8;
    int vs = tid&63, vd0 = (tid>>6)*8;
    int br = tid>>2, bhf = (tid&3)*16;
    const _Float16* kbase = kbuf + ((size_t)(b*Tt + kr))*NFf + h*DKk + kseg;
    const _Float16* vbase = vbuf + ((size_t)(b*Tt + vs))*NFf + h*DKk + vd0;
    const _Float16* bbase = Sb + (((size_t)((t0+br)*64 + bh))<<10) + bhf;

    // prefetch + stage chunk 0 into buffer 0
    v8h pk = *(const v8h*)kbase;
    v8h pv = *(const v8h*)vbase;
    v8h pb0 = *(const v8h*)bbase;
    v8h pb1 = *((const v8h*)bbase + 1);
    st8(&Kl[0][swz(kr, kseg)], pk);
    #pragma unroll
    for (int j=0;j<8;j++) Vt[0][swz(vd0+j, vs)] = pv[j];
    st8(&Bl[0][swz(br, bhf)],   pb0);
    st8(&Bl[0][swz(br, bhf+8)], pb1);
    __syncthreads();

    for (int sc=0; sc<16; ++sc){
        int cur = sc&1;
        if (sc < 15){
            size_t soff = (size_t)(sc+1)*64;
            pk  = *(const v8h*)(kbase + soff*NFf);
            pv  = *(const v8h*)(vbase + soff*NFf);
            pb0 = *(const v8h*)(bbase + soff);
            pb1 = *((const v8h*)(bbase + soff) + 1);
        }

        v4f sv[4];
        #pragma unroll
        for (int nt=0; nt<4; ++nt){
            v8h kb0 = *(v8h*)&Kl[cur][swz(nt*16+l15, lq*8)];
            v8h kb1 = *(v8h*)&Kl[cur][swz(nt*16+l15, 32+lq*8)];
            v4f a = {};
            a = MFMA32(kb0, qa[0], a);
            a = MFMA32(kb1, qa[1], a);
            v4h bl4 = *(v4h*)&Bl[cur][swz(w*16 + l15, nt*16 + lq*4)];
            #pragma unroll
            for (int i=0;i<4;i++) a[i] += (float)bl4[i];
            sv[nt] = a;
        }
        float mx = fmaxf(fmaxf(fmaxf(sv[0][0],sv[0][1]),fmaxf(sv[0][2],sv[0][3])),
                   fmaxf(fmaxf(fmaxf(sv[1][0],sv[1][1]),fmaxf(sv[1][2],sv[1][3])),
                   fmaxf(fmaxf(fmaxf(sv[2][0],sv[2][1]),fmaxf(sv[2][2],sv[2][3])),
                         fmaxf(fmaxf(sv[3][0],sv[3][1]),fmaxf(sv[3][2],sv[3][3])))));
        mx = fmaxf(mx, __shfl_xor(mx,16));
        mx = fmaxf(mx, __shfl_xor(mx,32));
        float mn = fmaxf(m_l, mx);
        if (__any(mn - m_l > 0.f)){
            float rsc = exp2f(m_l - mn);
            m_l = mn; l_l *= rsc;
            float rscB[4];
            #pragma unroll
            for (int i=0;i<4;i++) rscB[i] = __shfl(rsc, lq*4+i);
            #pragma unroll
            for (int nt=0; nt<4; ++nt)
                #pragma unroll
                for (int i=0;i<4;i++) O[nt][i] *= rscB[i];
        }
        float ps = 0.f;
        #pragma unroll
        for (int nt=0; nt<4; ++nt){
            v4h ph;
            #pragma unroll
            for (int i=0;i<4;i++){
                float p = exp2f(sv[nt][i] - m_l);
                ph[i] = (_Float16)p;
                ps += p;
            }
            *(v4h*)&Bl[cur][swz(w*16 + l15, nt*16 + lq*4)] = ph;   // wave-private rows
        }
        ps += __shfl_xor(ps,16);
        ps += __shfl_xor(ps,32);
        l_l += ps;
        {
            v8h pa0 = *(v8h*)&Bl[cur][swz(w*16+l15, lq*8)];
            v8h pa1 = *(v8h*)&Bl[cur][swz(w*16+l15, 32+lq*8)];
            #pragma unroll
            for (int nt=0; nt<4; ++nt){
                v8h vb0 = *(v8h*)&Vt[cur][swz(nt*16+l15, lq*8)];
                v8h vb1 = *(v8h*)&Vt[cur][swz(nt*16+l15, 32+lq*8)];
                O[nt] = MFMA32(pa0, vb0, O[nt]);
                O[nt] = MFMA32(pa1, vb1, O[nt]);
            }
        }
        if (sc < 15){
            st8(&Kl[cur^1][swz(kr, kseg)], pk);
            #pragma unroll
            for (int j=0;j<8;j++) Vt[cur^1][swz(vd0+j, vs)] = pv[j];
            st8(&Bl[cur^1][swz(br, bhf)],   pb0);
            st8(&Bl[cur^1][swz(br, bhf+8)], pb1);
        }
        __syncthreads();
    }

    float rl = (l_l > 0.f) ? 1.f/l_l : 0.f;
    float rlB[4];
    #pragma unroll
    for (int i=0;i<4;i++) rlB[i] = __shfl(rl, lq*4+i);
    #pragma unroll
    for (int i=0;i<4;i++){
        int row = t0 + w*16 + lq*4 + i;
        #pragma unroll
        for (int nt=0; nt<4; ++nt)
            ao[((size_t)(b*Tt + row))*NFf + h*DKk + nt*16 + l15] = (_Float16)(O[nt][i]*rlB[i]);
    }
}

// ---------------- launch ----------------
extern "C" void kernel_launch(void* const* d_in, const int* in_sizes, int n_in,
                              void* d_out, int out_size, void* d_ws, size_t ws_size,
                              hipStream_t stream) {
    const float* x       = (const float*)d_in[0];
    const float* cond    = (const float*)d_in[1];
    const float* pos_k   = (const float*)d_in[2];
    const int*   mask    = (const int*)  d_in[3];
    const float* ln_g    = (const float*)d_in[4];
    const float* ln_b    = (const float*)d_in[5];
    const float* Wq      = (const float*)d_in[6];
    const float* bq      = (const float*)d_in[7];
    const float* Wk      = (const float*)d_in[8];
    const float* bk      = (const float*)d_in[9];
    const float* Wv      = (const float*)d_in[10];
    const float* bv      = (const float*)d_in[11];
    const float* Wo      = (const float*)d_in[12];
    const float* bo      = (const float*)d_in[13];
    const float* Wc      = (const float*)d_in[14];
    const float* bc      = (const float*)d_in[15];
    float* out = (float*)d_out;

    char* base = (char*)d_ws;
    const size_t OFF_S    = 0;                       // 134217728 B fp16 Sb
    const size_t OFF_XN   = 134217728;
    const size_t OFF_Q    = OFF_XN  + 8388608;
    const size_t OFF_QB   = OFF_Q   + 8388608;
    const size_t OFF_K    = OFF_QB  + 8388608;
    const size_t OFF_V    = OFF_K   + 8388608;
    const size_t OFF_AO   = OFF_V   + 8388608;
    const size_t OFF_WKT  = OFF_AO  + 8388608;       // 524288
    const size_t OFF_WVT  = OFF_WKT + 524288;
    const size_t OFF_WOT  = OFF_WVT + 524288;
    const size_t OFF_WQT  = OFF_WOT + 524288;        // 524288
    const size_t OFF_WCH  = OFF_WQT + 524288;        // 262144
    const size_t OFF_WCQT = OFF_WCH + 262144;        // 262144
    const size_t OFF_BCQ  = OFF_WCQT + 262144;       // 2048
    const size_t OFF_ZERO = OFF_BCQ + 2048;          // 1024

    _Float16* xn    = (_Float16*)(base + OFF_XN);
    _Float16* qbuf  = (_Float16*)(base + OFF_Q);
    _Float16* qb    = (_Float16*)(base + OFF_QB);
    _Float16* kb    = (_Float16*)(base + OFF_K);
    _Float16* vb    = (_Float16*)(base + OFF_V);
    _Float16* ao    = (_Float16*)(base + OFF_AO);
    _Float16* Sb    = (_Float16*)(base + OFF_S);
    _Float16* WkT   = (_Float16*)(base + OFF_WKT);
    _Float16* WvT   = (_Float16*)(base + OFF_WVT);
    _Float16* WoT   = (_Float16*)(base + OFF_WOT);
    _Float16* WqT   = (_Float16*)(base + OFF_WQT);
    _Float16* WcH   = (_Float16*)(base + OFF_WCH);
    _Float16* wcqT  = (_Float16*)(base + OFF_WCQT);
    float*    bcq   = (float*)(base + OFF_BCQ);
    float*    zero  = (float*)(base + OFF_ZERO);

    // front: weight prep (blocks 0..319) + LayerNorm (blocks 320..8511)
    k_front<<<dim3(8512), dim3(256), 0, stream>>>(x, ln_g, ln_b, xn,
                                                  Wk, Wv, Wo, Wq, WkT, WvT, WoT, WqT,
                                                  Wc, WcH, bq, bcq, zero);
    k_bcqp<<<dim3(16), dim3(512), 0, stream>>>(bc, Wq, bcq);

    // wcqT(512x256) = WqT(512x512) @ WcH(256x512)^T  via GEMM v3
    k_gemm<_Float16,_Float16,false><<<dim3(2,4), dim3(512), 0, stream>>>(WqT, WcH, zero, wcqT, 512, 256, 512, 1.f, nullptr);

    // q projection: writes scaled qbuf AND scaled transposed qb
    k_gemm<float,_Float16,true><<<dim3(4,64), dim3(512), 0, stream>>>(cond, wcqT, bcq, qbuf, Bb*Tt, 512, 256, SCQ, qb);
    // fused K+V projection
    k_gemmkv<<<dim3(4,64), dim3(512), 0, stream>>>(xn, WkT, WvT, bk, bv, kb, vb);

    k_bias<<<dim3(2048), dim3(256), 0, stream>>>(qb, pos_k, mask, Sb);
    k_flash<<<dim3(64,8), dim3(512), 0, stream>>>(qbuf, kb, vb, Sb, ao);

    k_gemm<_Float16,float,false><<<dim3(4,64), dim3(512), 0, stream>>>(ao, WoT, bo, out, Bb*Tt, 512, 512, 1.f, nullptr);
}

// Round 18
// 184.143 us; speedup vs baseline: 1.2157x; 1.1335x over previous
//
#include <hip/hip_runtime.h>

// ---------------- problem constants ----------------
#define Bb 8
#define Tt 1024
#define Hh 8
#define DKk 64
#define NFf 512
#define DCc 256

typedef _Float16 v2h __attribute__((ext_vector_type(2)));
typedef _Float16 v4h __attribute__((ext_vector_type(4)));
typedef _Float16 v8h __attribute__((ext_vector_type(8)));
typedef float    v4f __attribute__((ext_vector_type(4)));
typedef float    v16f __attribute__((ext_vector_type(16)));

#define MFMA32(a,b,c) __builtin_amdgcn_mfma_f32_16x16x32_f16((a),(b),(c),0,0,0)
#define MFMA3216(a,b,c) __builtin_amdgcn_mfma_f32_32x32x16_f16((a),(b),(c),0,0,0)

// scale folded into q: 1/sqrt(64) * log2(e)  (scores live in log2 domain)
#define SCQ 0.1803368801111f

__device__ inline void st8(_Float16* dst, v8h x){
    *(v4h*)dst     = __builtin_shufflevector(x,x,0,1,2,3);
    *(v4h*)(dst+4) = __builtin_shufflevector(x,x,4,5,6,7);
}

__device__ inline v8h cvt8(float4 a, float4 b){
    v8h r;
    r[0]=(_Float16)a.x; r[1]=(_Float16)a.y; r[2]=(_Float16)a.z; r[3]=(_Float16)a.w;
    r[4]=(_Float16)b.x; r[5]=(_Float16)b.y; r[6]=(_Float16)b.z; r[7]=(_Float16)b.w;
    return r;
}

__device__ inline v4f ntl4(const float* p){
    return __builtin_nontemporal_load(reinterpret_cast<const v4f*>(p));
}

// XOR swizzle for [R][64] half LDS tiles; keeps 8-half granularity
__device__ inline int swz(int r, int c){ return (r*64 + c) ^ ((r&7)<<3); }

// ---------------- front: [0,320) weight prep ; [320,8512) LayerNorm ----------
__global__ __launch_bounds__(256) void k_front(const float* __restrict__ x,
                                               const float* __restrict__ g,
                                               const float* __restrict__ be,
                                               _Float16* __restrict__ xn,
                                               const float* __restrict__ Wk,
                                               const float* __restrict__ Wv,
                                               const float* __restrict__ Wo,
                                               const float* __restrict__ Wq,
                                               _Float16* __restrict__ WkT,
                                               _Float16* __restrict__ WvT,
                                               _Float16* __restrict__ WoT,
                                               _Float16* __restrict__ WqT,
                                               const float* __restrict__ Wc,
                                               _Float16* __restrict__ WcH,
                                               const float* __restrict__ bq,
                                               float* __restrict__ bcq,
                                               float* __restrict__ zero){
    __shared__ float smem[64*65];
    int bid = blockIdx.x;
    int tid = threadIdx.x;
    if (bid < 320){
        int z = bid >> 6;          // 0..4
        int xy = bid & 63;
        if (z < 4){
            const float* W = (z==0)?Wk:(z==1)?Wv:(z==2)?Wo:Wq;
            _Float16*  WT = (z==0)?WkT:(z==1)?WvT:(z==2)?WoT:WqT;
            int bx = (xy&7)*64, by = (xy>>3)*64;
            int c = tid&63;
            float (*tile)[65] = (float(*)[65])smem;
            for (int r = tid>>6; r<64; r+=4) tile[r][c] = W[(size_t)(by+r)*512 + bx + c];
            __syncthreads();
            for (int n = tid>>6; n<64; n+=4) WT[(size_t)(bx+n)*512 + by + c] = (_Float16)tile[c][n];
        } else {
            int i = (xy*256 + tid)*8;
            float4 a = *(const float4*)(Wc+i);
            float4 b2 = *(const float4*)(Wc+i+4);
            *(v8h*)(WcH+i) = cvt8(a,b2);
            if (xy == 0) zero[tid] = 0.f;
            if (xy == 1){ bcq[tid] = bq[tid]; bcq[tid+256] = bq[tid+256]; }
        }
        return;
    }
    // LayerNorm
    int row = bid - 320;
    const float* xr = x + (size_t)row*512;
    float2 v = reinterpret_cast<const float2*>(xr)[tid];
    float s = v.x + v.y, sq = v.x*v.x + v.y*v.y;
    for (int off=32; off; off>>=1){ s += __shfl_down(s, off); sq += __shfl_down(sq, off); }
    int wid = tid>>6, lid = tid&63;
    if (lid==0){ smem[wid]=s; smem[4+wid]=sq; }
    __syncthreads();
    if (tid==0){
        float S=0,Q=0;
        for(int i=0;i<4;i++){S+=smem[i];Q+=smem[4+i];}
        float mu = S*(1.f/512.f);
        float var = Q*(1.f/512.f)-mu*mu;
        smem[8]=mu; smem[9]=rsqrtf(var+1e-5f);
    }
    __syncthreads();
    float mu=smem[8], rs=smem[9];
    float2 gv = reinterpret_cast<const float2*>(g)[tid];
    float2 bv = reinterpret_cast<const float2*>(be)[tid];
    v2h o; o[0] = (_Float16)((v.x-mu)*rs*gv.x + bv.x);
           o[1] = (_Float16)((v.y-mu)*rs*gv.y + bv.y);
    reinterpret_cast<v2h*>(xn + (size_t)row*512)[tid] = o;
}

// ---------------- bcq partial dots: bcq[j] += sum_{m in block} bc[m]*Wq[m][j]
__global__ __launch_bounds__(512) void k_bcqp(const float* __restrict__ bc,
                                              const float* __restrict__ Wq,
                                              float* __restrict__ bcq){
    int j = threadIdx.x; int m0 = blockIdx.x*16;
    float a = 0.f;
    #pragma unroll
    for (int m=0;m<16;m++) a += bc[m0+m]*Wq[(size_t)(m0+m)*512 + j];
    atomicAdd(&bcq[j], a);
}

// ---------------- GEMM v3: 128x128 tile, 512 thr, dbuf LDS + reg prefetch ----
template<typename AT, typename CT>
__global__ __launch_bounds__(512) void k_gemm(const AT* __restrict__ A,
                                              const _Float16* __restrict__ WT,
                                              const float* __restrict__ bias,
                                              CT* __restrict__ C,
                                              int M, int N, int K,
                                              float scale){
    __shared__ _Float16 Al[2][128*64];
    __shared__ _Float16 Wl[2][128*64];
    int tid = threadIdx.x, l = tid&63, w = tid>>6;
    int l15 = l&15, lq = l>>4;
    int wr = w>>2, wc = w&3;
    int m0 = blockIdx.y*128, n0 = blockIdx.x*128;
    v4f acc[4][2] = {};
    float bv[2];
    #pragma unroll
    for (int bc=0;bc<2;++bc) bv[bc] = bias[n0 + wc*32 + bc*16 + l15];
    int srow = tid>>2, sseg = (tid&3)*16;
    const AT* arow = A + (size_t)(m0+srow)*K + sseg;
    const _Float16* wrow = WT + (size_t)(n0+srow)*K + sseg;
    int NT = K>>6;

    v8h pa0, pa1, pw0, pw1;
    if constexpr (sizeof(AT)==4){
        const float* s = (const float*)arow;
        pa0 = cvt8(*(const float4*)s,     *(const float4*)(s+4));
        pa1 = cvt8(*(const float4*)(s+8), *(const float4*)(s+12));
    } else {
        pa0 = *(const v8h*)arow; pa1 = *(const v8h*)(arow+8);
    }
    pw0 = *(const v8h*)wrow; pw1 = *(const v8h*)(wrow+8);
    st8(&Al[0][swz(srow,sseg)], pa0); st8(&Al[0][swz(srow,sseg+8)], pa1);
    st8(&Wl[0][swz(srow,sseg)], pw0); st8(&Wl[0][swz(srow,sseg+8)], pw1);
    __syncthreads();

    for (int kt=0; kt<NT; ++kt){
        int cur = kt&1;
        if (kt < NT-1){
            int k0 = (kt+1)<<6;
            if constexpr (sizeof(AT)==4){
                const float* s = (const float*)arow + k0;
                pa0 = cvt8(*(const float4*)s,     *(const float4*)(s+4));
                pa1 = cvt8(*(const float4*)(s+8), *(const float4*)(s+12));
            } else {
                pa0 = *(const v8h*)(arow + k0); pa1 = *(const v8h*)(arow + k0 + 8);
            }
            pw0 = *(const v8h*)(wrow + k0); pw1 = *(const v8h*)(wrow + k0 + 8);
        }
        #pragma unroll
        for (int kk=0; kk<2; ++kk){
            v8h af[4], bf[2];
            #pragma unroll
            for (int ar=0;ar<4;++ar) af[ar] = *(v8h*)&Al[cur][swz(wr*64+ar*16+l15, kk*32+lq*8)];
            #pragma unroll
            for (int bc=0;bc<2;++bc) bf[bc] = *(v8h*)&Wl[cur][swz(wc*32+bc*16+l15, kk*32+lq*8)];
            #pragma unroll
            for (int ar=0;ar<4;++ar)
                #pragma unroll
                for (int bc=0;bc<2;++bc)
                    acc[ar][bc] = MFMA32(af[ar], bf[bc], acc[ar][bc]);
        }
        if (kt < NT-1){
            st8(&Al[cur^1][swz(srow,sseg)], pa0); st8(&Al[cur^1][swz(srow,sseg+8)], pa1);
            st8(&Wl[cur^1][swz(srow,sseg)], pw0); st8(&Wl[cur^1][swz(srow,sseg+8)], pw1);
        }
        __syncthreads();
    }
    #pragma unroll
    for (int ar=0;ar<4;++ar){
        #pragma unroll
        for (int bc=0;bc<2;++bc){
            #pragma unroll
            for (int i=0;i<4;++i){
                int row = m0 + wr*64 + ar*16 + lq*4 + i;
                int col = n0 + wc*32 + bc*16 + l15;
                float vf = (acc[ar][bc][i] + bv[bc])*scale;
                C[(size_t)row*N + col] = (CT)vf;
            }
        }
    }
}

// ---------------- fused K+V projection v3: same structure, two W streams -----
__global__ __launch_bounds__(512) void k_gemmkv(const _Float16* __restrict__ A,
                                                const _Float16* __restrict__ WTk,
                                                const _Float16* __restrict__ WTv,
                                                const float* __restrict__ bk,
                                                const float* __restrict__ bv,
                                                _Float16* __restrict__ Ck,
                                                _Float16* __restrict__ Cv){
    __shared__ _Float16 Al[2][128*64];
    __shared__ _Float16 Wkl[2][128*64];
    __shared__ _Float16 Wvl[2][128*64];
    int tid = threadIdx.x, l = tid&63, w = tid>>6;
    int l15 = l&15, lq = l>>4;
    int wr = w>>2, wc = w&3;
    int m0 = blockIdx.y*128, n0 = blockIdx.x*128;
    v4f ack[4][2] = {}, acv[4][2] = {};
    float bkr[2], bvr[2];
    #pragma unroll
    for (int bc=0;bc<2;++bc){ bkr[bc] = bk[n0 + wc*32 + bc*16 + l15]; bvr[bc] = bv[n0 + wc*32 + bc*16 + l15]; }
    int srow = tid>>2, sseg = (tid&3)*16;
    const _Float16* arow = A   + (size_t)(m0+srow)*512 + sseg;
    const _Float16* krow = WTk + (size_t)(n0+srow)*512 + sseg;
    const _Float16* vrow = WTv + (size_t)(n0+srow)*512 + sseg;

    v8h pa0,pa1,pk0,pk1,pv0,pv1;
    pa0 = *(const v8h*)arow; pa1 = *(const v8h*)(arow+8);
    pk0 = *(const v8h*)krow; pk1 = *(const v8h*)(krow+8);
    pv0 = *(const v8h*)vrow; pv1 = *(const v8h*)(vrow+8);
    st8(&Al[0][swz(srow,sseg)],  pa0); st8(&Al[0][swz(srow,sseg+8)],  pa1);
    st8(&Wkl[0][swz(srow,sseg)], pk0); st8(&Wkl[0][swz(srow,sseg+8)], pk1);
    st8(&Wvl[0][swz(srow,sseg)], pv0); st8(&Wvl[0][swz(srow,sseg+8)], pv1);
    __syncthreads();

    for (int kt=0; kt<8; ++kt){
        int cur = kt&1;
        if (kt < 7){
            int k0 = (kt+1)<<6;
            pa0 = *(const v8h*)(arow+k0); pa1 = *(const v8h*)(arow+k0+8);
            pk0 = *(const v8h*)(krow+k0); pk1 = *(const v8h*)(krow+k0+8);
            pv0 = *(const v8h*)(vrow+k0); pv1 = *(const v8h*)(vrow+k0+8);
        }
        #pragma unroll
        for (int kk=0; kk<2; ++kk){
            v8h af[4], kf[2], vf[2];
            #pragma unroll
            for (int ar=0;ar<4;++ar) af[ar] = *(v8h*)&Al[cur][swz(wr*64+ar*16+l15, kk*32+lq*8)];
            #pragma unroll
            for (int bc=0;bc<2;++bc){
                kf[bc] = *(v8h*)&Wkl[cur][swz(wc*32+bc*16+l15, kk*32+lq*8)];
                vf[bc] = *(v8h*)&Wvl[cur][swz(wc*32+bc*16+l15, kk*32+lq*8)];
            }
            #pragma unroll
            for (int ar=0;ar<4;++ar)
                #pragma unroll
                for (int bc=0;bc<2;++bc){
                    ack[ar][bc] = MFMA32(af[ar], kf[bc], ack[ar][bc]);
                    acv[ar][bc] = MFMA32(af[ar], vf[bc], acv[ar][bc]);
                }
        }
        if (kt < 7){
            st8(&Al[cur^1][swz(srow,sseg)],  pa0); st8(&Al[cur^1][swz(srow,sseg+8)],  pa1);
            st8(&Wkl[cur^1][swz(srow,sseg)], pk0); st8(&Wkl[cur^1][swz(srow,sseg+8)], pk1);
            st8(&Wvl[cur^1][swz(srow,sseg)], pv0); st8(&Wvl[cur^1][swz(srow,sseg+8)], pv1);
        }
        __syncthreads();
    }
    #pragma unroll
    for (int ar=0;ar<4;++ar){
        #pragma unroll
        for (int bc=0;bc<2;++bc){
            #pragma unroll
            for (int i=0;i<4;++i){
                int row = m0 + wr*64 + ar*16 + lq*4 + i;
                int col = n0 + wc*32 + bc*16 + l15;
                Ck[(size_t)row*512 + col] = (_Float16)(ack[ar][bc][i] + bkr[bc]);
                Cv[(size_t)row*512 + col] = (_Float16)(acv[ar][bc][i] + bvr[bc]);
            }
        }
    }
}

// ---------------- bias v9: A-frags from qbuf, NT posk, 17 KB LDS -------------
// 8 blocks/CU. Race audit as v8: Pl reads before barrier-A, Pl writes after A;
// Ol writes before A, reads between A/B.
__global__ __launch_bounds__(256) void k_bias(const _Float16* __restrict__ qbuf,
                                              const float* __restrict__ posk,
                                              const int* __restrict__ mask,
                                              _Float16* __restrict__ Sb){
    __shared__ _Float16 Pl[64*64];   // posk chunk [s][d] fp16, swizzled
    __shared__ _Float16 Ol[64*72];   // out tile [bh][s], pad 72
    int t = blockIdx.x >> 1, sh = blockIdx.x & 1;
    int tid = threadIdx.x, l = tid&63, w = tid>>6;
    int l31 = l&31, hi = l>>5;
    int g = w & 1, sg = w >> 1;      // wave's bh-group / s-subgroup
    // A-frags direct from qbuf: bh = g*32+l31 -> b = bh>>3, h = bh&7
    v8h aa[4];
    {
        int bh = g*32 + l31; int bI = bh>>3, hI = bh&7;
        const _Float16* qrow = qbuf + ((size_t)(bI*Tt + t))*NFf + hI*DKk + hi*8;
        #pragma unroll
        for (int k0=0;k0<4;++k0)
            aa[k0] = *(const v8h*)(qrow + k0*16);
    }

    const float* pkt = posk + ((size_t)t<<16);
    int sbase = sh*512;
    int lrow = (l>>4), lcol = (l&15)*4;      // within-wave load geometry

    v4f pf[4];
    #pragma unroll
    for (int j=0;j<4;++j)
        pf[j] = ntl4(pkt + (size_t)(sbase + w*16 + j*4 + lrow)*64 + lcol);

    int obh = tid>>2;
    int osl = (tid&3)*16;
    int ob  = obh>>3;
    const int* mbase = mask + (((size_t)(ob*Tt + t))<<10);
    _Float16* sbb = Sb + (((size_t)(t*64 + obh))<<10);

    // stage chunk0
    #pragma unroll
    for (int j=0;j<4;++j){
        v4h hv; hv[0]=(_Float16)pf[j][0]; hv[1]=(_Float16)pf[j][1];
                hv[2]=(_Float16)pf[j][2]; hv[3]=(_Float16)pf[j][3];
        *(v4h*)&Pl[swz(w*16 + j*4 + lrow, lcol)] = hv;
    }
    __syncthreads();

    for (int sc=0; sc<8; ++sc){
        int s0 = sbase + sc*64;
        if (sc < 7){
            #pragma unroll
            for (int j=0;j<4;++j)
                pf[j] = ntl4(pkt + (size_t)(s0 + 64 + w*16 + j*4 + lrow)*64 + lcol);
        }
        int4 mq[4];
        #pragma unroll
        for (int j=0;j<4;++j)
            mq[j] = *(const int4*)(mbase + s0 + osl + j*4);
        v8h bfr[4];
        #pragma unroll
        for (int k0=0;k0<4;++k0)
            bfr[k0] = *(v8h*)&Pl[swz(sg*32 + l31, k0*16 + hi*8)];
        v16f acc = {};
        #pragma unroll
        for (int k0=0;k0<4;++k0) acc = MFMA3216(aa[k0], bfr[k0], acc);
        #pragma unroll
        for (int r=0;r<16;++r){
            int bh = g*32 + (r&3) + 4*hi + 8*(r>>2);
            Ol[bh*72 + sg*32 + l31] = (_Float16)acc[r];
        }
        __syncthreads();   // A: Pl reads + Ol writes complete
        if (sc < 7){
            #pragma unroll
            for (int j=0;j<4;++j){
                v4h hv; hv[0]=(_Float16)pf[j][0]; hv[1]=(_Float16)pf[j][1];
                        hv[2]=(_Float16)pf[j][2]; hv[3]=(_Float16)pf[j][3];
                *(v4h*)&Pl[swz(w*16 + j*4 + lrow, lcol)] = hv;
            }
        }
        v8h o0 = *(v8h*)&Ol[obh*72 + osl];
        v8h o1 = *(v8h*)&Ol[obh*72 + osl + 8];
        const _Float16 NEG = (_Float16)(-30000.f);
        int mm[16] = {mq[0].x,mq[0].y,mq[0].z,mq[0].w, mq[1].x,mq[1].y,mq[1].z,mq[1].w,
                      mq[2].x,mq[2].y,mq[2].z,mq[2].w, mq[3].x,mq[3].y,mq[3].z,mq[3].w};
        #pragma unroll
        for (int j=0;j<8;++j){ if(!mm[j]) o0[j]=NEG; if(!mm[8+j]) o1[j]=NEG; }
        *(v8h*)(sbb + s0 + osl)     = o0;
        *(v8h*)(sbb + s0 + osl + 8) = o1;
        __syncthreads();   // B: Ol reads + Pl writes complete
    }
}

// ---------------- flash v4: swapped QK + dbuf LDS, 1 barrier/chunk -----------
__global__ __launch_bounds__(512) void k_flash(const _Float16* __restrict__ qs,
                                               const _Float16* __restrict__ kbuf,
                                               const _Float16* __restrict__ vbuf,
                                               const _Float16* __restrict__ Sb,
                                               _Float16* __restrict__ ao){
    __shared__ _Float16 Kl[2][64*64];    // [s][d] swizzled
    __shared__ _Float16 Vt[2][64*64];    // [d][s] swizzled
    __shared__ _Float16 Bl[2][128*64];   // bias chunk then P (wave-private rows)
    int bh = blockIdx.x; int b = bh>>3, h = bh&7;
    int t0 = blockIdx.y*128;
    int tid = threadIdx.x, l = tid&63, w = tid>>6, l15 = l&15, lq = l>>4;

    v8h qa[2];
    #pragma unroll
    for (int u=0;u<2;++u)
        qa[u] = *(const v8h*)(qs + ((size_t)(b*Tt + t0 + w*16 + l15))*NFf + h*DKk + u*32 + lq*8);

    v4f O[4] = {};
    float m_l = -1e30f, l_l = 0.f;

    int kr = tid>>3, kseg = (tid&7)*8;
    int vs = tid&63, vd0 = (tid>>6)*8;
    int br = tid>>2, bhf = (tid&3)*16;
    const _Float16* kbase = kbuf + ((size_t)(b*Tt + kr))*NFf + h*DKk + kseg;
    const _Float16* vbase = vbuf + ((size_t)(b*Tt + vs))*NFf + h*DKk + vd0;
    const _Float16* bbase = Sb + (((size_t)((t0+br)*64 + bh))<<10) + bhf;

    v8h pk = *(const v8h*)kbase;
    v8h pv = *(const v8h*)vbase;
    v8h pb0 = *(const v8h*)bbase;
    v8h pb1 = *((const v8h*)bbase + 1);
    st8(&Kl[0][swz(kr, kseg)], pk);
    #pragma unroll
    for (int j=0;j<8;j++) Vt[0][swz(vd0+j, vs)] = pv[j];
    st8(&Bl[0][swz(br, bhf)],   pb0);
    st8(&Bl[0][swz(br, bhf+8)], pb1);
    __syncthreads();

    for (int sc=0; sc<16; ++sc){
        int cur = sc&1;
        if (sc < 15){
            size_t soff = (size_t)(sc+1)*64;
            pk  = *(const v8h*)(kbase + soff*NFf);
            pv  = *(const v8h*)(vbase + soff*NFf);
            pb0 = *(const v8h*)(bbase + soff);
            pb1 = *((const v8h*)(bbase + soff) + 1);
        }

        v4f sv[4];
        #pragma unroll
        for (int nt=0; nt<4; ++nt){
            v8h kb0 = *(v8h*)&Kl[cur][swz(nt*16+l15, lq*8)];
            v8h kb1 = *(v8h*)&Kl[cur][swz(nt*16+l15, 32+lq*8)];
            v4f a = {};
            a = MFMA32(kb0, qa[0], a);
            a = MFMA32(kb1, qa[1], a);
            v4h bl4 = *(v4h*)&Bl[cur][swz(w*16 + l15, nt*16 + lq*4)];
            #pragma unroll
            for (int i=0;i<4;i++) a[i] += (float)bl4[i];
            sv[nt] = a;
        }
        float mx = fmaxf(fmaxf(fmaxf(sv[0][0],sv[0][1]),fmaxf(sv[0][2],sv[0][3])),
                   fmaxf(fmaxf(fmaxf(sv[1][0],sv[1][1]),fmaxf(sv[1][2],sv[1][3])),
                   fmaxf(fmaxf(fmaxf(sv[2][0],sv[2][1]),fmaxf(sv[2][2],sv[2][3])),
                         fmaxf(fmaxf(sv[3][0],sv[3][1]),fmaxf(sv[3][2],sv[3][3])))));
        mx = fmaxf(mx, __shfl_xor(mx,16));
        mx = fmaxf(mx, __shfl_xor(mx,32));
        float mn = fmaxf(m_l, mx);
        if (__any(mn - m_l > 0.f)){
            float rsc = exp2f(m_l - mn);
            m_l = mn; l_l *= rsc;
            float rscB[4];
            #pragma unroll
            for (int i=0;i<4;i++) rscB[i] = __shfl(rsc, lq*4+i);
            #pragma unroll
            for (int nt=0; nt<4; ++nt)
                #pragma unroll
                for (int i=0;i<4;i++) O[nt][i] *= rscB[i];
        }
        float ps = 0.f;
        #pragma unroll
        for (int nt=0; nt<4; ++nt){
            v4h ph;
            #pragma unroll
            for (int i=0;i<4;i++){
                float p = exp2f(sv[nt][i] - m_l);
                ph[i] = (_Float16)p;
                ps += p;
            }
            *(v4h*)&Bl[cur][swz(w*16 + l15, nt*16 + lq*4)] = ph;   // wave-private rows
        }
        ps += __shfl_xor(ps,16);
        ps += __shfl_xor(ps,32);
        l_l += ps;
        {
            v8h pa0 = *(v8h*)&Bl[cur][swz(w*16+l15, lq*8)];
            v8h pa1 = *(v8h*)&Bl[cur][swz(w*16+l15, 32+lq*8)];
            #pragma unroll
            for (int nt=0; nt<4; ++nt){
                v8h vb0 = *(v8h*)&Vt[cur][swz(nt*16+l15, lq*8)];
                v8h vb1 = *(v8h*)&Vt[cur][swz(nt*16+l15, 32+lq*8)];
                O[nt] = MFMA32(pa0, vb0, O[nt]);
                O[nt] = MFMA32(pa1, vb1, O[nt]);
            }
        }
        if (sc < 15){
            st8(&Kl[cur^1][swz(kr, kseg)], pk);
            #pragma unroll
            for (int j=0;j<8;j++) Vt[cur^1][swz(vd0+j, vs)] = pv[j];
            st8(&Bl[cur^1][swz(br, bhf)],   pb0);
            st8(&Bl[cur^1][swz(br, bhf+8)], pb1);
        }
        __syncthreads();
    }

    float rl = (l_l > 0.f) ? 1.f/l_l : 0.f;
    float rlB[4];
    #pragma unroll
    for (int i=0;i<4;i++) rlB[i] = __shfl(rl, lq*4+i);
    #pragma unroll
    for (int i=0;i<4;i++){
        int row = t0 + w*16 + lq*4 + i;
        #pragma unroll
        for (int nt=0; nt<4; ++nt)
            ao[((size_t)(b*Tt + row))*NFf + h*DKk + nt*16 + l15] = (_Float16)(O[nt][i]*rlB[i]);
    }
}

// ---------------- launch ----------------
extern "C" void kernel_launch(void* const* d_in, const int* in_sizes, int n_in,
                              void* d_out, int out_size, void* d_ws, size_t ws_size,
                              hipStream_t stream) {
    const float* x       = (const float*)d_in[0];
    const float* cond    = (const float*)d_in[1];
    const float* pos_k   = (const float*)d_in[2];
    const int*   mask    = (const int*)  d_in[3];
    const float* ln_g    = (const float*)d_in[4];
    const float* ln_b    = (const float*)d_in[5];
    const float* Wq      = (const float*)d_in[6];
    const float* bq      = (const float*)d_in[7];
    const float* Wk      = (const float*)d_in[8];
    const float* bk      = (const float*)d_in[9];
    const float* Wv      = (const float*)d_in[10];
    const float* bv      = (const float*)d_in[11];
    const float* Wo      = (const float*)d_in[12];
    const float* bo      = (const float*)d_in[13];
    const float* Wc      = (const float*)d_in[14];
    const float* bc      = (const float*)d_in[15];
    float* out = (float*)d_out;

    char* base = (char*)d_ws;
    const size_t OFF_S    = 0;                       // 134217728 B fp16 Sb
    const size_t OFF_XN   = 134217728;
    const size_t OFF_Q    = OFF_XN  + 8388608;
    const size_t OFF_K    = OFF_Q   + 8388608;
    const size_t OFF_V    = OFF_K   + 8388608;
    const size_t OFF_AO   = OFF_V   + 8388608;
    const size_t OFF_WKT  = OFF_AO  + 8388608;       // 524288
    const size_t OFF_WVT  = OFF_WKT + 524288;
    const size_t OFF_WOT  = OFF_WVT + 524288;
    const size_t OFF_WQT  = OFF_WOT + 524288;        // 524288
    const size_t OFF_WCH  = OFF_WQT + 524288;        // 262144
    const size_t OFF_WCQT = OFF_WCH + 262144;        // 262144
    const size_t OFF_BCQ  = OFF_WCQT + 262144;       // 2048
    const size_t OFF_ZERO = OFF_BCQ + 2048;          // 1024

    _Float16* xn    = (_Float16*)(base + OFF_XN);
    _Float16* qbuf  = (_Float16*)(base + OFF_Q);
    _Float16* kb    = (_Float16*)(base + OFF_K);
    _Float16* vb    = (_Float16*)(base + OFF_V);
    _Float16* ao    = (_Float16*)(base + OFF_AO);
    _Float16* Sb    = (_Float16*)(base + OFF_S);
    _Float16* WkT   = (_Float16*)(base + OFF_WKT);
    _Float16* WvT   = (_Float16*)(base + OFF_WVT);
    _Float16* WoT   = (_Float16*)(base + OFF_WOT);
    _Float16* WqT   = (_Float16*)(base + OFF_WQT);
    _Float16* WcH   = (_Float16*)(base + OFF_WCH);
    _Float16* wcqT  = (_Float16*)(base + OFF_WCQT);
    float*    bcq   = (float*)(base + OFF_BCQ);
    float*    zero  = (float*)(base + OFF_ZERO);

    // front: weight prep (blocks 0..319) + LayerNorm (blocks 320..8511)
    k_front<<<dim3(8512), dim3(256), 0, stream>>>(x, ln_g, ln_b, xn,
                                                  Wk, Wv, Wo, Wq, WkT, WvT, WoT, WqT,
                                                  Wc, WcH, bq, bcq, zero);
    k_bcqp<<<dim3(16), dim3(512), 0, stream>>>(bc, Wq, bcq);

    // wcqT(512x256) = WqT(512x512) @ WcH(256x512)^T  via GEMM v3
    k_gemm<_Float16,_Float16><<<dim3(2,4), dim3(512), 0, stream>>>(WqT, WcH, zero, wcqT, 512, 256, 512, 1.f);

    // q projection (scaled): qbuf only (k_bias reads frags from qbuf directly)
    k_gemm<float,_Float16><<<dim3(4,64), dim3(512), 0, stream>>>(cond, wcqT, bcq, qbuf, Bb*Tt, 512, 256, SCQ);
    // fused K+V projection
    k_gemmkv<<<dim3(4,64), dim3(512), 0, stream>>>(xn, WkT, WvT, bk, bv, kb, vb);

    k_bias<<<dim3(2048), dim3(256), 0, stream>>>(qbuf, pos_k, mask, Sb);
    k_flash<<<dim3(64,8), dim3(512), 0, stream>>>(qbuf, kb, vb, Sb, ao);

    k_gemm<_Float16,float><<<dim3(4,64), dim3(512), 0, stream>>>(ao, WoT, bo, out, Bb*Tt, 512, 512, 1.f);
}